// Round 8
// baseline (254.686 us; speedup 1.0000x reference)
//
#include <hip/hip_runtime.h>
#include <math.h>

#define BATCH 8
#define CH    256
#define HWN   4096
#define DQK   16

typedef __attribute__((ext_vector_type(8))) short short8;
typedef __attribute__((ext_vector_type(4))) float float4v;

#define L2E 1.4426950408889634f

__device__ __forceinline__ unsigned short f2bf(float f) {
    union { float f; unsigned int u; } v; v.f = f;
    unsigned int r = v.u + 0x7FFF + ((v.u >> 16) & 1);   // RNE
    return (unsigned short)(r >> 16);
}
// HW packed f32->bf16 convert (RNE): %1 -> low16, %2 -> high16
__device__ __forceinline__ unsigned int cvtpk(float lo, float hi) {
    unsigned int r;
    asm("v_cvt_pk_bf16_f32 %0, %1, %2" : "=v"(r) : "v"(lo), "v"(hi));
    return r;
}
// 2^x via hardware v_exp_f32, compiler-managed TRANS hazards
__device__ __forceinline__ float ex2(float x) {
#if __has_builtin(__builtin_amdgcn_exp2f)
    return __builtin_amdgcn_exp2f(x);
#else
    return exp2f(x);
#endif
}
// Block barrier WITHOUT the vmcnt(0) drain __syncthreads carries (T4):
// only LDS ordering is required for the pB exchange; global prefetches
// stay in flight across the barrier.
__device__ __forceinline__ void lds_barrier() {
    asm volatile("s_waitcnt lgkmcnt(0)" ::: "memory");
    __builtin_amdgcn_s_barrier();
}
// ft row permutation: stored row s holds key m with s4=m2, s3=m4, s2=m3
// (bits 0,1,5+ unchanged). Makes S^T output registers align with PV B-frag
// slots in the SAME lane (no cross-lane transpose needed).
__device__ __forceinline__ int perm_ft(int m) {
    return (m & ~28) | ((m & 24) >> 1) | ((m & 4) << 2);
}

// ---------------- kernel 0: W_cat -> bf16, biases -> bcat ----------------
__global__ __launch_bounds__(256) void wcast_kernel(
    const float* __restrict__ Wf, const float* __restrict__ bf_,
    const float* __restrict__ Wg, const float* __restrict__ bg,
    const float* __restrict__ Wh, const float* __restrict__ bh,
    unsigned short* __restrict__ Wbf, float* __restrict__ bcat)
{
    const int r = blockIdx.x;   // 288 rows
    const int t = threadIdx.x;  // 256 cols
    const float* src = (r < 16) ? (Wf + r*CH) : (r < 32) ? (Wg + (r-16)*CH) : (Wh + (r-32)*CH);
    Wbf[r*CH + t] = f2bf(src[t]);
    if (t == 0) bcat[r] = (r < 16) ? bf_[r] : (r < 32) ? bg[r-16] : bh[r-32];
}

// ---------------- kernel 1: x[b][c][px] fp32 -> xt[b][px][c] bf16 ----------------
// float4 global loads (coalesced 256B/16 lanes), cvt_pk convert, dword LDS
// reads in phase 2 (pad 74 keeps rows 4B-aligned, ~2-way banks max).
__global__ __launch_bounds__(256) void xt_kernel(const float* __restrict__ x,
                                                 unsigned short* __restrict__ xt)
{
    const int t  = threadIdx.x;
    const int p0 = blockIdx.x * 64;
    const int c0 = blockIdx.y * 64;
    const int b  = blockIdx.z;
    __shared__ unsigned short tile[64][74];
    const int col4 = (t & 15) * 4;          // px base within tile
    const int cr   = t >> 4;                // 0..15
    #pragma unroll
    for (int j = 0; j < 4; j++) {
        int c = cr + j*16;
        float4 v = *(const float4*)&x[(size_t)(b*CH + c0 + c)*HWN + p0 + col4];
        unsigned int u01 = cvtpk(v.x, v.y), u23 = cvtpk(v.z, v.w);
        tile[col4+0][c] = (unsigned short)u01;
        tile[col4+1][c] = (unsigned short)(u01 >> 16);
        tile[col4+2][c] = (unsigned short)u23;
        tile[col4+3][c] = (unsigned short)(u23 >> 16);
    }
    __syncthreads();
    const int pr = t >> 2;
    const int cb = (t & 3) * 16;
    unsigned int outv[8];
    #pragma unroll
    for (int i = 0; i < 8; i++)
        outv[i] = *(const unsigned int*)&tile[pr][cb + 2*i];
    unsigned short* dst = &xt[(size_t)(b*HWN + p0 + pr)*CH + c0 + cb];
    *(uint4*)dst       = *(uint4*)&outv[0];
    *(uint4*)(dst + 8) = *(uint4*)&outv[4];
}

// ---------------- kernel 2: MFMA projection, rt-split x3 ----------------
// Grid (64 px-blocks, 8 b, 3 rt-groups of 6). C[288][4096] = Wbf @ bf16(x).
// A-frags direct from xt, B-frags direct from L2-hot Wbf. Group 0 holds
// ft (rt 0, perm_ft rows, PRE-SCALED by log2e for exp2 in attn) and g
// (rt 1); h rows -> h3 fragment layout.
__global__ __launch_bounds__(256, 6) void proj_kernel(
    const unsigned short* __restrict__ xt, const unsigned short* __restrict__ Wbf,
    const float* __restrict__ bcat,
    unsigned short* __restrict__ ft, unsigned short* __restrict__ g,
    unsigned short* __restrict__ h3)
{
    const int t      = threadIdx.x;
    const int px0    = blockIdx.x * 64;
    const int b      = blockIdx.y;
    const int rtbase = blockIdx.z * 6;
    const int lane = t & 63, w = t >> 6, l15 = lane & 15, quad = lane >> 4;

    float4v acc[6];
    #pragma unroll
    for (int rt = 0; rt < 6; rt++) acc[rt] = (float4v){0.f,0.f,0.f,0.f};

    const unsigned short* xrow = &xt[((size_t)(b*HWN + px0 + w*16 + l15))*CH + quad*8];
    const unsigned short* wrow = &Wbf[(size_t)l15*CH + quad*8];

    #pragma unroll
    for (int ks = 0; ks < 8; ks++) {
        short8 afrag = *(const short8*)&xrow[ks*32];
        #pragma unroll
        for (int rt = 0; rt < 6; rt++) {
            short8 bfrag = *(const short8*)&wrow[(size_t)(rtbase + rt)*16*CH + ks*32];
            acc[rt] = __builtin_amdgcn_mfma_f32_16x16x32_bf16(afrag, bfrag, acc[rt], 0, 0, 0);
        }
    }

    const int pxl = px0 + w*16 + quad*4;      // this lane's px base (+r)
    const int mt  = (px0 >> 5) + (w >> 1);
    const int sub = ((w & 1)*2 + (quad >> 1))*128 + l15*8 + (quad & 1)*4;
    #pragma unroll
    for (int rt = 0; rt < 6; rt++) {
        const int R = rtbase + rt;            // uniform
        if (R == 0) {                         // -> ft at perm_ft rows, * log2e
            float bv = bcat[l15];
            const int s0 = perm_ft(pxl);      // r only touches bits 0,1
            unsigned int p01 = cvtpk((acc[rt][0] + bv)*L2E, (acc[rt][1] + bv)*L2E);
            unsigned int p23 = cvtpk((acc[rt][2] + bv)*L2E, (acc[rt][3] + bv)*L2E);
            unsigned short* fp0 = &ft[((size_t)b*HWN + s0)*32];
            fp0[l15]       = (unsigned short)p01;         fp0[16 + l15]  = 0;
            fp0[32 + l15]  = (unsigned short)(p01 >> 16); fp0[48 + l15]  = 0;
            fp0[64 + l15]  = (unsigned short)p23;         fp0[80 + l15]  = 0;
            fp0[96 + l15]  = (unsigned short)(p23 >> 16); fp0[112 + l15] = 0;
        } else if (R == 1) {                  // -> g (4 consecutive px: uint2)
            float bv = bcat[16 + l15];
            unsigned int a01 = cvtpk(acc[rt][0] + bv, acc[rt][1] + bv);
            unsigned int a23 = cvtpk(acc[rt][2] + bv, acc[rt][3] + bv);
            *(uint2*)&g[(size_t)(b*DQK + l15)*HWN + pxl] = make_uint2(a01, a23);
        } else {                              // -> h3 frag layout
            float bv = bcat[R*16 + l15];
            unsigned int u0 = cvtpk(acc[rt][0] + bv, acc[rt][1] + bv);
            unsigned int u1 = cvtpk(acc[rt][2] + bv, acc[rt][3] + bv);
            *(uint2*)&h3[(((size_t)((b*128 + mt)*16 + (R-2))) << 9) + sub] = make_uint2(u0, u1);
        }
    }
}

// ---------------- kernel 3: MFMA flash attention, 8 waves ----------------
// Block = 512 thr, (batch, 64-q tile), grid 512. R4/R7 dataflow.
// R8: R7's VGPR=60 exposed that the compiler SANK the hr/fr "prefetch"
// loads to their uses (true dbuf needs ~100 VGPR live). Fixes:
//  (1) sched_barrier(0) after the pre-barrier prefetch issues pins them
//      early; they stay in flight across the lgkm-only barrier.
//  (2) pB 4-buffer rotation; P(i+1) written right after S^T(i+1), off the
//      barrier edge (pre-barrier tail = pure PV). WAR distance = 3 iters.
//  (3) bq reads grouped per-grp (4 x ds_read_b128 then 8 MFMA).
// TELL: VGPR should rise to ~100-115. WRITE_SIZE must stay ~32.8 MB (R3
// spill lesson).
__global__ __launch_bounds__(512, 4) void attn_kernel(
    const unsigned short* __restrict__ ft, const unsigned short* __restrict__ g,
    const unsigned short* __restrict__ h3, const float* __restrict__ x,
    const float* __restrict__ gamma_p, float* __restrict__ out)
{
    const int t    = threadIdx.x;
    const int b    = blockIdx.x & 7;          // batch -> XCD pin
    const int q0   = (blockIdx.x >> 3) * 64;
    const int lane = t & 63, w = t >> 6, l15 = lane & 15, quad = lane >> 4;
    const int qt_w = w >> 1, half = w & 1;

    __shared__ __align__(16) uint4 pB[4][2][4][64];   // [buf][half][qt][lane] 32 KB
    __shared__ float l_l[4][16][2];

    union { short8 v; unsigned short u[8]; } gfrag;   // B[k=quad*8+j][q=l15] of q-tile qt_w
    #pragma unroll
    for (int j = 0; j < 8; j++) {
        int k = quad*8 + j;
        gfrag.u[j] = (k < DQK) ? g[(size_t)(b*DQK + k)*HWN + q0 + qt_w*16 + l15] : (unsigned short)0;
    }

    const unsigned short* ftb = ft + (size_t)b*HWN*32;
    const unsigned short* h3b = h3 + ((size_t)b << 20);

    short8 fr[2][2], hr[2][2][2];
    float4v acc[2][4];
    #pragma unroll
    for (int i = 0; i < 2; i++)
        #pragma unroll
        for (int j = 0; j < 4; j++) acc[i][j] = (float4v){0.f,0.f,0.f,0.f};
    float l_acc = 0.f;
    uint4 P;

    // ---- prologue: fr[0] <- f(0); S^T(0)+exp2 -> P; pB[0] = P;
    //      fr[1] <- f(1); hr[0] <- h(0) ----
    #pragma unroll
    for (int j = 0; j < 2; j++)
        fr[0][j] = *(const short8*)&ftb[(size_t)((half*2 + j)*16 + l15)*32 + quad*8];
    {
        float4v z = {0.f,0.f,0.f,0.f};
        float4v s0v = __builtin_amdgcn_mfma_f32_16x16x32_bf16(fr[0][0], gfrag.v, z, 0, 0, 0);
        float4v s1v = __builtin_amdgcn_mfma_f32_16x16x32_bf16(fr[0][1], gfrag.v, z, 0, 0, 0);
        float e0 = ex2(s0v[0]), e1 = ex2(s0v[1]), e2 = ex2(s0v[2]), e3 = ex2(s0v[3]);
        float e4 = ex2(s1v[0]), e5 = ex2(s1v[1]), e6 = ex2(s1v[2]), e7 = ex2(s1v[3]);
        l_acc += (e0 + e1) + (e2 + e3) + (e4 + e5) + (e6 + e7);
        P = make_uint4(cvtpk(e0, e1), cvtpk(e2, e3), cvtpk(e4, e5), cvtpk(e6, e7));
    }
    pB[0][half][qt_w][lane] = P;
    #pragma unroll
    for (int j = 0; j < 2; j++)
        fr[1][j] = *(const short8*)&ftb[(size_t)(64 + (half*2 + j)*16 + l15)*32 + quad*8];
    #pragma unroll
    for (int grp = 0; grp < 2; grp++)
        #pragma unroll
        for (int ctl = 0; ctl < 2; ctl++)
            hr[0][grp][ctl] = *(const short8*)&h3b[(((size_t)(grp*16 + w*2 + ctl)) << 9) + lane*8];

    // Step i (u=i&1, up=i&3 read-buf, un=(i+1)&3 write-buf):
    //  pre-barrier: hr[u^1] <- h(i+1), fr[u] <- f(i+2), sched_barrier(0)
    //  lds_barrier (pB[up] visible; globals stay in flight)
    //  S^T(i+1) from fr[u^1] -> exp2 -> P; pB[un] = P (overlaps PV)
    //  PV(i): per grp {4 x bq from pB[up]; 8 MFMA} under setprio(1)
    // WARs: fr[u] last read at step i-1's S^T (program order); hr[u^1] last
    // read at step i-1's PV; pB[un] last read at step i-3's PV (3 barriers
    // back). Dead slop reads at steps 62 (f(64)) stay inside ws.
#define ATTN_STEP(u, up, un, i, DO_NEXT) do {                                  \
    if (DO_NEXT) {                                                             \
      const int nh = (i) + 1;                                                  \
      _Pragma("unroll")                                                        \
      for (int grp = 0; grp < 2; grp++)                                        \
        _Pragma("unroll")                                                      \
        for (int ctl = 0; ctl < 2; ctl++)                                      \
          hr[(u)^1][grp][ctl] = *(const short8*)&h3b[(((size_t)((nh*2 + grp)*16 + w*2 + ctl)) << 9) + lane*8]; \
      const int nf = (i) + 2;                                                  \
      _Pragma("unroll")                                                        \
      for (int j = 0; j < 2; j++)                                              \
        fr[u][j] = *(const short8*)&ftb[(size_t)(nf*64 + (half*2 + j)*16 + l15)*32 + quad*8]; \
      __builtin_amdgcn_sched_barrier(0);                                       \
    }                                                                          \
    lds_barrier();                                                             \
    if (DO_NEXT) {                                                             \
      float4v z = {0.f,0.f,0.f,0.f};                                           \
      float4v s0v = __builtin_amdgcn_mfma_f32_16x16x32_bf16(fr[(u)^1][0], gfrag.v, z, 0, 0, 0); \
      float4v s1v = __builtin_amdgcn_mfma_f32_16x16x32_bf16(fr[(u)^1][1], gfrag.v, z, 0, 0, 0); \
      float e0 = ex2(s0v[0]), e1 = ex2(s0v[1]), e2 = ex2(s0v[2]), e3 = ex2(s0v[3]); \
      float e4 = ex2(s1v[0]), e5 = ex2(s1v[1]), e6 = ex2(s1v[2]), e7 = ex2(s1v[3]); \
      l_acc += (e0 + e1) + (e2 + e3) + (e4 + e5) + (e6 + e7);                  \
      P = make_uint4(cvtpk(e0, e1), cvtpk(e2, e3), cvtpk(e4, e5), cvtpk(e6, e7)); \
      pB[un][half][qt_w][lane] = P;                                            \
    }                                                                          \
    __builtin_amdgcn_s_setprio(1);                                             \
    _Pragma("unroll")                                                          \
    for (int grp = 0; grp < 2; grp++) {                                        \
      union { uint4 uu; short8 v; } bq0, bq1, bq2, bq3;                        \
      bq0.uu = pB[up][grp][0][lane];                                           \
      bq1.uu = pB[up][grp][1][lane];                                           \
      bq2.uu = pB[up][grp][2][lane];                                           \
      bq3.uu = pB[up][grp][3][lane];                                           \
      _Pragma("unroll")                                                        \
      for (int ctl = 0; ctl < 2; ctl++) {                                      \
        acc[ctl][0] = __builtin_amdgcn_mfma_f32_16x16x32_bf16(hr[u][grp][ctl], bq0.v, acc[ctl][0], 0, 0, 0); \
        acc[ctl][1] = __builtin_amdgcn_mfma_f32_16x16x32_bf16(hr[u][grp][ctl], bq1.v, acc[ctl][1], 0, 0, 0); \
        acc[ctl][2] = __builtin_amdgcn_mfma_f32_16x16x32_bf16(hr[u][grp][ctl], bq2.v, acc[ctl][2], 0, 0, 0); \
        acc[ctl][3] = __builtin_amdgcn_mfma_f32_16x16x32_bf16(hr[u][grp][ctl], bq3.v, acc[ctl][3], 0, 0, 0); \
      }                                                                        \
    }                                                                          \
    __builtin_amdgcn_s_setprio(0);                                             \
  } while (0)

    for (int i0 = 0; i0 < 60; i0 += 4) {
        ATTN_STEP(0, 0, 1, i0 + 0, 1);
        ATTN_STEP(1, 1, 2, i0 + 1, 1);
        ATTN_STEP(0, 2, 3, i0 + 2, 1);
        ATTN_STEP(1, 3, 0, i0 + 3, 1);
    }
    ATTN_STEP(0, 0, 1, 60, 1);
    ATTN_STEP(1, 1, 2, 61, 1);
    ATTN_STEP(0, 2, 3, 62, 1);   // S^T(63) -> pB[3]; f(64) prefetch = dead slop
    ATTN_STEP(1, 3, 0, 63, 0);   // peeled tail: PV(63) from pB[3] only
#undef ATTN_STEP

    // ---- l: reduce over quads; combine halves via LDS ----
    l_acc += __shfl_xor(l_acc, 16, 64);
    l_acc += __shfl_xor(l_acc, 32, 64);
    if (quad == 0) l_l[qt_w][l15][half] = l_acc;
    __syncthreads();

    const float gamma = *gamma_p;
    float linv[4];
    #pragma unroll
    for (int qt = 0; qt < 4; qt++) linv[qt] = 1.f / (l_l[qt][l15][0] + l_l[qt][l15][1]);
    #pragma unroll
    for (int ctl = 0; ctl < 2; ctl++) {
        #pragma unroll
        for (int r = 0; r < 4; r++) {
            int c = w*32 + ctl*16 + quad*4 + r;
            size_t base = (size_t)(b*CH + c)*HWN + q0;
            #pragma unroll
            for (int qt = 0; qt < 4; qt++) {
                size_t o = base + qt*16 + l15;
                out[o] = gamma * acc[ctl][qt][r] * linv[qt] + x[o];
            }
        }
    }
}

extern "C" void kernel_launch(void* const* d_in, const int* in_sizes, int n_in,
                              void* d_out, int out_size, void* d_ws, size_t ws_size,
                              hipStream_t stream) {
    const float* x     = (const float*)d_in[0];
    const float* Wf    = (const float*)d_in[1];
    const float* bf_   = (const float*)d_in[2];
    const float* Wg    = (const float*)d_in[3];
    const float* bg    = (const float*)d_in[4];
    const float* Wh    = (const float*)d_in[5];
    const float* bh    = (const float*)d_in[6];
    const float* gamma = (const float*)d_in[7];
    float* out = (float*)d_out;

    // ws: xt 16.8MB | ft 2MB | g 1MB | h3 16.8MB | Wbf 147KB | bcat
    unsigned short* xt   = (unsigned short*)d_ws;
    unsigned short* ftp  = xt  + (size_t)BATCH*HWN*CH;
    unsigned short* g    = ftp + (size_t)BATCH*HWN*32;
    unsigned short* h3   = g   + (size_t)BATCH*DQK*HWN;
    unsigned short* Wbf  = h3  + (size_t)BATCH*128*16*512;
    float*          bcat = (float*)(Wbf + 288*CH);

    wcast_kernel<<<dim3(288), 256, 0, stream>>>(Wf, bf_, Wg, bg, Wh, bh, Wbf, bcat);
    xt_kernel<<<dim3(HWN/64, CH/64, BATCH), 256, 0, stream>>>(x, xt);
    proj_kernel<<<dim3(HWN/64, BATCH, 3), 256, 0, stream>>>(xt, Wbf, bcat, ftp, g, h3);
    attn_kernel<<<dim3((HWN/64)*BATCH), 512, 0, stream>>>(ftp, g, h3, x, gamma, out);
}

// Round 9
// 220.435 us; speedup vs baseline: 1.1554x; 1.1554x over previous
//
#include <hip/hip_runtime.h>
#include <math.h>

#define BATCH 8
#define CH    256
#define HWN   4096
#define DQK   16

typedef __attribute__((ext_vector_type(8))) short short8;
typedef __attribute__((ext_vector_type(4))) float float4v;

#define L2E 1.4426950408889634f

__device__ __forceinline__ unsigned short f2bf(float f) {
    union { float f; unsigned int u; } v; v.f = f;
    unsigned int r = v.u + 0x7FFF + ((v.u >> 16) & 1);   // RNE
    return (unsigned short)(r >> 16);
}
// HW packed f32->bf16 convert (RNE): %1 -> low16, %2 -> high16
__device__ __forceinline__ unsigned int cvtpk(float lo, float hi) {
    unsigned int r;
    asm("v_cvt_pk_bf16_f32 %0, %1, %2" : "=v"(r) : "v"(lo), "v"(hi));
    return r;
}
// 2^x via hardware v_exp_f32, compiler-managed TRANS hazards
__device__ __forceinline__ float ex2(float x) {
#if __has_builtin(__builtin_amdgcn_exp2f)
    return __builtin_amdgcn_exp2f(x);
#else
    return exp2f(x);
#endif
}
// Block barrier WITHOUT the vmcnt(0) drain __syncthreads carries (T4):
// only LDS ordering is required for the pB exchange; global prefetches
// stay in flight across the barrier.
__device__ __forceinline__ void lds_barrier() {
    asm volatile("s_waitcnt lgkmcnt(0)" ::: "memory");
    __builtin_amdgcn_s_barrier();
}
// ft row permutation: stored row s holds key m with s4=m2, s3=m4, s2=m3
// (bits 0,1,5+ unchanged). Makes S^T output registers align with PV B-frag
// slots in the SAME lane (no cross-lane transpose needed).
__device__ __forceinline__ int perm_ft(int m) {
    return (m & ~28) | ((m & 24) >> 1) | ((m & 4) << 2);
}

// ---------------- kernel 0: W_cat -> bf16, biases -> bcat ----------------
__global__ __launch_bounds__(256) void wcast_kernel(
    const float* __restrict__ Wf, const float* __restrict__ bf_,
    const float* __restrict__ Wg, const float* __restrict__ bg,
    const float* __restrict__ Wh, const float* __restrict__ bh,
    unsigned short* __restrict__ Wbf, float* __restrict__ bcat)
{
    const int r = blockIdx.x;   // 288 rows
    const int t = threadIdx.x;  // 256 cols
    const float* src = (r < 16) ? (Wf + r*CH) : (r < 32) ? (Wg + (r-16)*CH) : (Wh + (r-32)*CH);
    Wbf[r*CH + t] = f2bf(src[t]);
    if (t == 0) bcat[r] = (r < 16) ? bf_[r] : (r < 32) ? bg[r-16] : bh[r-32];
}

// ---------------- kernel 1: x[b][c][px] fp32 -> xt[b][px][c] bf16 ----------------
// float4 global loads (coalesced 256B/16 lanes), cvt_pk convert, dword LDS
// reads in phase 2 (pad 74 keeps rows 4B-aligned, ~2-way banks max).
__global__ __launch_bounds__(256) void xt_kernel(const float* __restrict__ x,
                                                 unsigned short* __restrict__ xt)
{
    const int t  = threadIdx.x;
    const int p0 = blockIdx.x * 64;
    const int c0 = blockIdx.y * 64;
    const int b  = blockIdx.z;
    __shared__ unsigned short tile[64][74];
    const int col4 = (t & 15) * 4;          // px base within tile
    const int cr   = t >> 4;                // 0..15
    #pragma unroll
    for (int j = 0; j < 4; j++) {
        int c = cr + j*16;
        float4 v = *(const float4*)&x[(size_t)(b*CH + c0 + c)*HWN + p0 + col4];
        unsigned int u01 = cvtpk(v.x, v.y), u23 = cvtpk(v.z, v.w);
        tile[col4+0][c] = (unsigned short)u01;
        tile[col4+1][c] = (unsigned short)(u01 >> 16);
        tile[col4+2][c] = (unsigned short)u23;
        tile[col4+3][c] = (unsigned short)(u23 >> 16);
    }
    __syncthreads();
    const int pr = t >> 2;
    const int cb = (t & 3) * 16;
    unsigned int outv[8];
    #pragma unroll
    for (int i = 0; i < 8; i++)
        outv[i] = *(const unsigned int*)&tile[pr][cb + 2*i];
    unsigned short* dst = &xt[(size_t)(b*HWN + p0 + pr)*CH + c0 + cb];
    *(uint4*)dst       = *(uint4*)&outv[0];
    *(uint4*)(dst + 8) = *(uint4*)&outv[4];
}

// ---------------- kernel 2: MFMA projection, rt-split x3 ----------------
// Grid (64 px-blocks, 8 b, 3 rt-groups of 6). C[288][4096] = Wbf @ bf16(x).
// A-frags direct from xt, B-frags direct from L2-hot Wbf. Group 0 holds
// ft (rt 0, perm_ft rows, PRE-SCALED by log2e for exp2 in attn) and g
// (rt 1); h rows -> h3 fragment layout.
__global__ __launch_bounds__(256, 6) void proj_kernel(
    const unsigned short* __restrict__ xt, const unsigned short* __restrict__ Wbf,
    const float* __restrict__ bcat,
    unsigned short* __restrict__ ft, unsigned short* __restrict__ g,
    unsigned short* __restrict__ h3)
{
    const int t      = threadIdx.x;
    const int px0    = blockIdx.x * 64;
    const int b      = blockIdx.y;
    const int rtbase = blockIdx.z * 6;
    const int lane = t & 63, w = t >> 6, l15 = lane & 15, quad = lane >> 4;

    float4v acc[6];
    #pragma unroll
    for (int rt = 0; rt < 6; rt++) acc[rt] = (float4v){0.f,0.f,0.f,0.f};

    const unsigned short* xrow = &xt[((size_t)(b*HWN + px0 + w*16 + l15))*CH + quad*8];
    const unsigned short* wrow = &Wbf[(size_t)l15*CH + quad*8];

    #pragma unroll
    for (int ks = 0; ks < 8; ks++) {
        short8 afrag = *(const short8*)&xrow[ks*32];
        #pragma unroll
        for (int rt = 0; rt < 6; rt++) {
            short8 bfrag = *(const short8*)&wrow[(size_t)(rtbase + rt)*16*CH + ks*32];
            acc[rt] = __builtin_amdgcn_mfma_f32_16x16x32_bf16(afrag, bfrag, acc[rt], 0, 0, 0);
        }
    }

    const int pxl = px0 + w*16 + quad*4;      // this lane's px base (+r)
    const int mt  = (px0 >> 5) + (w >> 1);
    const int sub = ((w & 1)*2 + (quad >> 1))*128 + l15*8 + (quad & 1)*4;
    #pragma unroll
    for (int rt = 0; rt < 6; rt++) {
        const int R = rtbase + rt;            // uniform
        if (R == 0) {                         // -> ft at perm_ft rows, * log2e
            float bv = bcat[l15];
            const int s0 = perm_ft(pxl);      // r only touches bits 0,1
            unsigned int p01 = cvtpk((acc[rt][0] + bv)*L2E, (acc[rt][1] + bv)*L2E);
            unsigned int p23 = cvtpk((acc[rt][2] + bv)*L2E, (acc[rt][3] + bv)*L2E);
            unsigned short* fp0 = &ft[((size_t)b*HWN + s0)*32];
            fp0[l15]       = (unsigned short)p01;         fp0[16 + l15]  = 0;
            fp0[32 + l15]  = (unsigned short)(p01 >> 16); fp0[48 + l15]  = 0;
            fp0[64 + l15]  = (unsigned short)p23;         fp0[80 + l15]  = 0;
            fp0[96 + l15]  = (unsigned short)(p23 >> 16); fp0[112 + l15] = 0;
        } else if (R == 1) {                  // -> g (4 consecutive px: uint2)
            float bv = bcat[16 + l15];
            unsigned int a01 = cvtpk(acc[rt][0] + bv, acc[rt][1] + bv);
            unsigned int a23 = cvtpk(acc[rt][2] + bv, acc[rt][3] + bv);
            *(uint2*)&g[(size_t)(b*DQK + l15)*HWN + pxl] = make_uint2(a01, a23);
        } else {                              // -> h3 frag layout
            float bv = bcat[R*16 + l15];
            unsigned int u0 = cvtpk(acc[rt][0] + bv, acc[rt][1] + bv);
            unsigned int u1 = cvtpk(acc[rt][2] + bv, acc[rt][3] + bv);
            *(uint2*)&h3[(((size_t)((b*128 + mt)*16 + (R-2))) << 9) + sub] = make_uint2(u0, u1);
        }
    }
}

// ---------------- kernel 3: MFMA flash attention, 8 waves ----------------
// Block = 512 thr, (batch, 64-q tile), grid 512.
// R9: barrier halving (64 -> 32) under strict register discipline.
// REGISTER CEILING (R3/R8 lesson): __launch_bounds__(512,4) caps the
// unified VGPR+AGPR budget at 128/wave; acc uses 32 AGPR -> ~96 VGPRs
// available. Structures above that SPILL (WRITE_SIZE tell). This design:
// frE/frO 16 + per-phase hr 16 + Pa/Pb 8 + gfrag 4 + addr ~20 ~= 64 VGPR.
// Super-iter T = tiles (2T, 2T+1), ONE lgkm-barrier each:
//   top:    write Pa->pB[b0], Pb->pB[b1]; barrier.  (b0,b1 = (T&1)*2 +{0,1};
//           WAR vs reads at T-2 separated by barrier(T-1))
//   phaseA: hr<-h3(2T); frO<-ft(2T+3); S^T(2T+2) from frE -> Pa; PV(2T)
//   phaseB: hr<-h3(2T+1); frE<-ft(2T+4); S^T(2T+3) from frO -> Pb; PV(2T+1)
// Sequential S^T keeps fr at 2x2 frags; hr declared in-phase (reg reuse).
__global__ __launch_bounds__(512, 4) void attn_kernel(
    const unsigned short* __restrict__ ft, const unsigned short* __restrict__ g,
    const unsigned short* __restrict__ h3, const float* __restrict__ x,
    const float* __restrict__ gamma_p, float* __restrict__ out)
{
    const int t    = threadIdx.x;
    const int b    = blockIdx.x & 7;          // batch -> XCD pin
    const int q0   = (blockIdx.x >> 3) * 64;
    const int lane = t & 63, w = t >> 6, l15 = lane & 15, quad = lane >> 4;
    const int qt_w = w >> 1, half = w & 1;

    __shared__ __align__(16) uint4 pB[4][2][4][64];   // [buf][half][qt][lane] 32 KB
    __shared__ float l_l[4][16][2];

    union { short8 v; unsigned short u[8]; } gfrag;   // B[k=quad*8+j][q=l15] of q-tile qt_w
    #pragma unroll
    for (int j = 0; j < 8; j++) {
        int k = quad*8 + j;
        gfrag.u[j] = (k < DQK) ? g[(size_t)(b*DQK + k)*HWN + q0 + qt_w*16 + l15] : (unsigned short)0;
    }

    const unsigned short* ftb = ft + (size_t)b*HWN*32;
    const unsigned short* h3b = h3 + ((size_t)b << 20);

    short8 frE[2], frO[2];
    float4v acc[2][4];
    #pragma unroll
    for (int i = 0; i < 2; i++)
        #pragma unroll
        for (int j = 0; j < 4; j++) acc[i][j] = (float4v){0.f,0.f,0.f,0.f};
    float l_acc = 0.f;
    uint4 Pa, Pb;

#define EXP2_PACK(sv0, sv1, Pout) do {                                         \
      float e0 = ex2((sv0)[0]), e1 = ex2((sv0)[1]), e2 = ex2((sv0)[2]), e3 = ex2((sv0)[3]); \
      float e4 = ex2((sv1)[0]), e5 = ex2((sv1)[1]), e6 = ex2((sv1)[2]), e7 = ex2((sv1)[3]); \
      l_acc += ((e0 + e1) + (e2 + e3)) + ((e4 + e5) + (e6 + e7));              \
      Pout = make_uint4(cvtpk(e0, e1), cvtpk(e2, e3), cvtpk(e4, e5), cvtpk(e6, e7)); \
    } while (0)

    // ---- prologue: Pa = P(0), Pb = P(1) via a dying temp; frE <- ft(2) ----
    {
        short8 f0[2];
        float4v z = {0.f,0.f,0.f,0.f};
        #pragma unroll
        for (int j = 0; j < 2; j++)
            f0[j] = *(const short8*)&ftb[(size_t)((half*2 + j)*16 + l15)*32 + quad*8];
        float4v s0 = __builtin_amdgcn_mfma_f32_16x16x32_bf16(f0[0], gfrag.v, z, 0, 0, 0);
        float4v s1 = __builtin_amdgcn_mfma_f32_16x16x32_bf16(f0[1], gfrag.v, z, 0, 0, 0);
        EXP2_PACK(s0, s1, Pa);
        #pragma unroll
        for (int j = 0; j < 2; j++)
            f0[j] = *(const short8*)&ftb[(size_t)(64 + (half*2 + j)*16 + l15)*32 + quad*8];
        s0 = __builtin_amdgcn_mfma_f32_16x16x32_bf16(f0[0], gfrag.v, z, 0, 0, 0);
        s1 = __builtin_amdgcn_mfma_f32_16x16x32_bf16(f0[1], gfrag.v, z, 0, 0, 0);
        EXP2_PACK(s0, s1, Pb);
    }
    #pragma unroll
    for (int j = 0; j < 2; j++)
        frE[j] = *(const short8*)&ftb[(size_t)(2*64 + (half*2 + j)*16 + l15)*32 + quad*8];

    // One PV phase: 16 MFMA from pB[buf] x hr, under setprio(1).
#define PV_PHASE(buf, hrv) do {                                                \
    __builtin_amdgcn_s_setprio(1);                                             \
    _Pragma("unroll")                                                          \
    for (int grp = 0; grp < 2; grp++) {                                        \
      _Pragma("unroll")                                                        \
      for (int qt = 0; qt < 4; qt++) {                                         \
        union { uint4 uu; short8 v; } bq;                                      \
        bq.uu = pB[buf][grp][qt][lane];                                        \
        _Pragma("unroll")                                                      \
        for (int ctl = 0; ctl < 2; ctl++)                                      \
          acc[ctl][qt] = __builtin_amdgcn_mfma_f32_16x16x32_bf16(hrv[grp][ctl], bq.v, acc[ctl][qt], 0, 0, 0); \
      }                                                                        \
    }                                                                          \
    __builtin_amdgcn_s_setprio(0);                                             \
  } while (0)

#define SUPER(b0, b1, T, DO_NEXT) do {                                         \
    pB[b0][half][qt_w][lane] = Pa;                                             \
    pB[b1][half][qt_w][lane] = Pb;                                             \
    lds_barrier();                                                             \
    { /* ---- phase A: tile 2T ---- */                                         \
      short8 hr[2][2];                                                         \
      _Pragma("unroll")                                                        \
      for (int grp = 0; grp < 2; grp++)                                        \
        _Pragma("unroll")                                                      \
        for (int ctl = 0; ctl < 2; ctl++)                                      \
          hr[grp][ctl] = *(const short8*)&h3b[(((size_t)((4*(T) + grp)*16 + w*2 + ctl)) << 9) + lane*8]; \
      if (DO_NEXT) {                                                           \
        _Pragma("unroll")                                                      \
        for (int j = 0; j < 2; j++)                                            \
          frO[j] = *(const short8*)&ftb[(size_t)((2*(T) + 3)*64 + (half*2 + j)*16 + l15)*32 + quad*8]; \
        float4v z = {0.f,0.f,0.f,0.f};                                         \
        float4v s0 = __builtin_amdgcn_mfma_f32_16x16x32_bf16(frE[0], gfrag.v, z, 0, 0, 0); \
        float4v s1 = __builtin_amdgcn_mfma_f32_16x16x32_bf16(frE[1], gfrag.v, z, 0, 0, 0); \
        EXP2_PACK(s0, s1, Pa);                                                 \
      }                                                                        \
      PV_PHASE(b0, hr);                                                        \
    }                                                                          \
    { /* ---- phase B: tile 2T+1 ---- */                                       \
      short8 hr[2][2];                                                         \
      _Pragma("unroll")                                                        \
      for (int grp = 0; grp < 2; grp++)                                        \
        _Pragma("unroll")                                                      \
        for (int ctl = 0; ctl < 2; ctl++)                                      \
          hr[grp][ctl] = *(const short8*)&h3b[(((size_t)((4*(T) + 2 + grp)*16 + w*2 + ctl)) << 9) + lane*8]; \
      if (DO_NEXT) {                                                           \
        _Pragma("unroll")                                                      \
        for (int j = 0; j < 2; j++)                                            \
          frE[j] = *(const short8*)&ftb[(size_t)((2*(T) + 4)*64 + (half*2 + j)*16 + l15)*32 + quad*8]; \
        float4v z = {0.f,0.f,0.f,0.f};                                         \
        float4v s0 = __builtin_amdgcn_mfma_f32_16x16x32_bf16(frO[0], gfrag.v, z, 0, 0, 0); \
        float4v s1 = __builtin_amdgcn_mfma_f32_16x16x32_bf16(frO[1], gfrag.v, z, 0, 0, 0); \
        EXP2_PACK(s0, s1, Pb);                                                 \
      }                                                                        \
      PV_PHASE(b1, hr);                                                        \
    }                                                                          \
  } while (0)

    for (int T = 0; T < 30; T += 2) {
        SUPER(0, 1, T, 1);
        SUPER(2, 3, T + 1, 1);
    }
    SUPER(0, 1, 30, 1);    // computes S^T(62),S^T(63); frE<-ft(64) is dead slop (in ws)
    SUPER(2, 3, 31, 0);    // peeled tail: write P(62),P(63); PV only
#undef SUPER
#undef PV_PHASE
#undef EXP2_PACK

    // ---- l: reduce over quads; combine halves via LDS ----
    l_acc += __shfl_xor(l_acc, 16, 64);
    l_acc += __shfl_xor(l_acc, 32, 64);
    if (quad == 0) l_l[qt_w][l15][half] = l_acc;
    __syncthreads();

    const float gamma = *gamma_p;
    float linv[4];
    #pragma unroll
    for (int qt = 0; qt < 4; qt++) linv[qt] = 1.f / (l_l[qt][l15][0] + l_l[qt][l15][1]);
    #pragma unroll
    for (int ctl = 0; ctl < 2; ctl++) {
        #pragma unroll
        for (int r = 0; r < 4; r++) {
            int c = w*32 + ctl*16 + quad*4 + r;
            size_t base = (size_t)(b*CH + c)*HWN + q0;
            #pragma unroll
            for (int qt = 0; qt < 4; qt++) {
                size_t o = base + qt*16 + l15;
                out[o] = gamma * acc[ctl][qt][r] * linv[qt] + x[o];
            }
        }
    }
}

extern "C" void kernel_launch(void* const* d_in, const int* in_sizes, int n_in,
                              void* d_out, int out_size, void* d_ws, size_t ws_size,
                              hipStream_t stream) {
    const float* x     = (const float*)d_in[0];
    const float* Wf    = (const float*)d_in[1];
    const float* bf_   = (const float*)d_in[2];
    const float* Wg    = (const float*)d_in[3];
    const float* bg    = (const float*)d_in[4];
    const float* Wh    = (const float*)d_in[5];
    const float* bh    = (const float*)d_in[6];
    const float* gamma = (const float*)d_in[7];
    float* out = (float*)d_out;

    // ws: xt 16.8MB | ft 2MB | g 1MB | h3 16.8MB | Wbf 147KB | bcat
    unsigned short* xt   = (unsigned short*)d_ws;
    unsigned short* ftp  = xt  + (size_t)BATCH*HWN*CH;
    unsigned short* g    = ftp + (size_t)BATCH*HWN*32;
    unsigned short* h3   = g   + (size_t)BATCH*DQK*HWN;
    unsigned short* Wbf  = h3  + (size_t)BATCH*128*16*512;
    float*          bcat = (float*)(Wbf + 288*CH);

    wcast_kernel<<<dim3(288), 256, 0, stream>>>(Wf, bf_, Wg, bg, Wh, bh, Wbf, bcat);
    xt_kernel<<<dim3(HWN/64, CH/64, BATCH), 256, 0, stream>>>(x, xt);
    proj_kernel<<<dim3(HWN/64, BATCH, 3), 256, 0, stream>>>(xt, Wbf, bcat, ftp, g, h3);
    attn_kernel<<<dim3((HWN/64)*BATCH), 512, 0, stream>>>(ftp, g, h3, x, gamma, out);
}

// Round 10
// 213.016 us; speedup vs baseline: 1.1956x; 1.0348x over previous
//
#include <hip/hip_runtime.h>
#include <math.h>

#define BATCH 8
#define CH    256
#define HWN   4096
#define DQK   16

typedef __attribute__((ext_vector_type(8))) short short8;
typedef __attribute__((ext_vector_type(4))) float float4v;

#define L2E 1.4426950408889634f

__device__ __forceinline__ unsigned short f2bf(float f) {
    union { float f; unsigned int u; } v; v.f = f;
    unsigned int r = v.u + 0x7FFF + ((v.u >> 16) & 1);   // RNE
    return (unsigned short)(r >> 16);
}
// HW packed f32->bf16 convert (RNE): %1 -> low16, %2 -> high16
__device__ __forceinline__ unsigned int cvtpk(float lo, float hi) {
    unsigned int r;
    asm("v_cvt_pk_bf16_f32 %0, %1, %2" : "=v"(r) : "v"(lo), "v"(hi));
    return r;
}
// 2^x via hardware v_exp_f32, compiler-managed TRANS hazards
__device__ __forceinline__ float ex2(float x) {
#if __has_builtin(__builtin_amdgcn_exp2f)
    return __builtin_amdgcn_exp2f(x);
#else
    return exp2f(x);
#endif
}
// Block barrier WITHOUT the vmcnt(0) drain __syncthreads carries (T4):
// only LDS ordering is required for the pB exchange; global prefetches
// stay in flight across the barrier.
__device__ __forceinline__ void lds_barrier() {
    asm volatile("s_waitcnt lgkmcnt(0)" ::: "memory");
    __builtin_amdgcn_s_barrier();
}
// ft row permutation: stored row s holds key m with s4=m2, s3=m4, s2=m3
// (bits 0,1,5+ unchanged). Makes S^T output registers align with PV B-frag
// slots in the SAME lane (no cross-lane transpose needed).
__device__ __forceinline__ int perm_ft(int m) {
    return (m & ~28) | ((m & 24) >> 1) | ((m & 4) << 2);
}

// ---------------- kernel 1: x transpose->bf16 + (48 blocks) W cast ----------------
// xt part: float4 global loads (coalesced), cvt_pk convert, dword LDS reads
// (pad 74). wcast part folded into blocks (z==0, y==0, x<48): 6 rows each
// of W_cat -> Wbf bf16 + bcat. Saves one kernel launch.
__global__ __launch_bounds__(256) void xt_wcast_kernel(
    const float* __restrict__ x,
    const float* __restrict__ Wf, const float* __restrict__ bf_,
    const float* __restrict__ Wg, const float* __restrict__ bg,
    const float* __restrict__ Wh, const float* __restrict__ bh,
    unsigned short* __restrict__ xt,
    unsigned short* __restrict__ Wbf, float* __restrict__ bcat)
{
    const int t  = threadIdx.x;
    const int p0 = blockIdx.x * 64;
    const int c0 = blockIdx.y * 64;
    const int b  = blockIdx.z;

    if (b == 0 && blockIdx.y == 0 && blockIdx.x < 48) {
        #pragma unroll
        for (int j = 0; j < 6; j++) {
            const int r = blockIdx.x * 6 + j;   // 0..287
            const float* src = (r < 16) ? (Wf + r*CH) : (r < 32) ? (Wg + (r-16)*CH) : (Wh + (r-32)*CH);
            Wbf[r*CH + t] = f2bf(src[t]);
            if (t == 0) bcat[r] = (r < 16) ? bf_[r] : (r < 32) ? bg[r-16] : bh[r-32];
        }
    }

    __shared__ unsigned short tile[64][74];
    const int col4 = (t & 15) * 4;          // px base within tile
    const int cr   = t >> 4;                // 0..15
    #pragma unroll
    for (int j = 0; j < 4; j++) {
        int c = cr + j*16;
        float4 v = *(const float4*)&x[(size_t)(b*CH + c0 + c)*HWN + p0 + col4];
        unsigned int u01 = cvtpk(v.x, v.y), u23 = cvtpk(v.z, v.w);
        tile[col4+0][c] = (unsigned short)u01;
        tile[col4+1][c] = (unsigned short)(u01 >> 16);
        tile[col4+2][c] = (unsigned short)u23;
        tile[col4+3][c] = (unsigned short)(u23 >> 16);
    }
    __syncthreads();
    const int pr = t >> 2;
    const int cb = (t & 3) * 16;
    unsigned int outv[8];
    #pragma unroll
    for (int i = 0; i < 8; i++)
        outv[i] = *(const unsigned int*)&tile[pr][cb + 2*i];
    unsigned short* dst = &xt[(size_t)(b*HWN + p0 + pr)*CH + c0 + cb];
    *(uint4*)dst       = *(uint4*)&outv[0];
    *(uint4*)(dst + 8) = *(uint4*)&outv[4];
}

// ---------------- kernel 2: MFMA projection, rt-split x2 ----------------
// Grid (64 px-blocks, 8 b, 2 rt-groups of 9) = 1024 blocks (4/CU).
// R10: 3->2 groups halves the redundant xt re-read (50->33.5 MB total).
// Register ceiling check (session lesson): __launch_bounds__(256,4) caps
// 128/wave; acc 9x4=36 AGPR + bfrag/afrag/addr ~55 VGPR ~= 91 < 128, no
// spill. Group 0 holds ft (rt 0, perm_ft rows, PRE-SCALED by log2e) and
// g (rt 1) + h rows 0..6; group 1 holds h rows 7..15.
__global__ __launch_bounds__(256, 4) void proj_kernel(
    const unsigned short* __restrict__ xt, const unsigned short* __restrict__ Wbf,
    const float* __restrict__ bcat,
    unsigned short* __restrict__ ft, unsigned short* __restrict__ g,
    unsigned short* __restrict__ h3)
{
    const int t      = threadIdx.x;
    const int px0    = blockIdx.x * 64;
    const int b      = blockIdx.y;
    const int rtbase = blockIdx.z * 9;
    const int lane = t & 63, w = t >> 6, l15 = lane & 15, quad = lane >> 4;

    float4v acc[9];
    #pragma unroll
    for (int rt = 0; rt < 9; rt++) acc[rt] = (float4v){0.f,0.f,0.f,0.f};

    const unsigned short* xrow = &xt[((size_t)(b*HWN + px0 + w*16 + l15))*CH + quad*8];
    const unsigned short* wrow = &Wbf[(size_t)l15*CH + quad*8];

    #pragma unroll
    for (int ks = 0; ks < 8; ks++) {
        short8 afrag = *(const short8*)&xrow[ks*32];
        #pragma unroll
        for (int rt = 0; rt < 9; rt++) {
            short8 bfrag = *(const short8*)&wrow[(size_t)(rtbase + rt)*16*CH + ks*32];
            acc[rt] = __builtin_amdgcn_mfma_f32_16x16x32_bf16(afrag, bfrag, acc[rt], 0, 0, 0);
        }
    }

    const int pxl = px0 + w*16 + quad*4;      // this lane's px base (+r)
    const int mt  = (px0 >> 5) + (w >> 1);
    const int sub = ((w & 1)*2 + (quad >> 1))*128 + l15*8 + (quad & 1)*4;
    #pragma unroll
    for (int rt = 0; rt < 9; rt++) {
        const int R = rtbase + rt;            // uniform
        if (R == 0) {                         // -> ft at perm_ft rows, * log2e
            float bv = bcat[l15];
            const int s0 = perm_ft(pxl);      // r only touches bits 0,1
            unsigned int p01 = cvtpk((acc[rt][0] + bv)*L2E, (acc[rt][1] + bv)*L2E);
            unsigned int p23 = cvtpk((acc[rt][2] + bv)*L2E, (acc[rt][3] + bv)*L2E);
            unsigned short* fp0 = &ft[((size_t)b*HWN + s0)*32];
            fp0[l15]       = (unsigned short)p01;         fp0[16 + l15]  = 0;
            fp0[32 + l15]  = (unsigned short)(p01 >> 16); fp0[48 + l15]  = 0;
            fp0[64 + l15]  = (unsigned short)p23;         fp0[80 + l15]  = 0;
            fp0[96 + l15]  = (unsigned short)(p23 >> 16); fp0[112 + l15] = 0;
        } else if (R == 1) {                  // -> g (4 consecutive px: uint2)
            float bv = bcat[16 + l15];
            unsigned int a01 = cvtpk(acc[rt][0] + bv, acc[rt][1] + bv);
            unsigned int a23 = cvtpk(acc[rt][2] + bv, acc[rt][3] + bv);
            *(uint2*)&g[(size_t)(b*DQK + l15)*HWN + pxl] = make_uint2(a01, a23);
        } else {                              // -> h3 frag layout
            float bv = bcat[R*16 + l15];
            unsigned int u0 = cvtpk(acc[rt][0] + bv, acc[rt][1] + bv);
            unsigned int u1 = cvtpk(acc[rt][2] + bv, acc[rt][3] + bv);
            *(uint2*)&h3[(((size_t)((b*128 + mt)*16 + (R-2))) << 9) + sub] = make_uint2(u0, u1);
        }
    }
}

// ---------------- kernel 3: MFMA flash attention, 8 waves ----------------
// FROZEN at R7 (best measured: 86.0 us, VGPR 60, no spill). Block = 512
// thr, (batch, 64-q tile), grid 512. 1 key-tile/barrier, pB[2] dbuf,
// software pipeline, lgkm-only barrier, pre-barrier hr prefetch, exp2 on
// L2E-prescaled ft, setprio around PV. Session lessons: >96 live VGPRs
// spills (R3/R8/R9); trading LDS reads for L2 loads regresses (R6);
// 32-q blocks halve arithmetic intensity (R5).
__global__ __launch_bounds__(512, 4) void attn_kernel(
    const unsigned short* __restrict__ ft, const unsigned short* __restrict__ g,
    const unsigned short* __restrict__ h3, const float* __restrict__ x,
    const float* __restrict__ gamma_p, float* __restrict__ out)
{
    const int t    = threadIdx.x;
    const int b    = blockIdx.x & 7;          // batch -> XCD pin
    const int q0   = (blockIdx.x >> 3) * 64;
    const int lane = t & 63, w = t >> 6, l15 = lane & 15, quad = lane >> 4;
    const int qt_w = w >> 1, half = w & 1;

    __shared__ __align__(16) uint4 pB[2][2][4][64];   // [buf][half][qt][lane] 16 KB
    __shared__ float l_l[4][16][2];

    union { short8 v; unsigned short u[8]; } gfrag;   // B[k=quad*8+j][q=l15] of q-tile qt_w
    #pragma unroll
    for (int j = 0; j < 8; j++) {
        int k = quad*8 + j;
        gfrag.u[j] = (k < DQK) ? g[(size_t)(b*DQK + k)*HWN + q0 + qt_w*16 + l15] : (unsigned short)0;
    }

    const unsigned short* ftb = ft + (size_t)b*HWN*32;
    const unsigned short* h3b = h3 + ((size_t)b << 20);

    short8 fr[2][2], hr[2][2][2];
    float4v acc[2][4];
    #pragma unroll
    for (int i = 0; i < 2; i++)
        #pragma unroll
        for (int j = 0; j < 4; j++) acc[i][j] = (float4v){0.f,0.f,0.f,0.f};
    float l_acc = 0.f;
    uint4 P;

    // ---- prologue: fr tile0 -> slot0, S^T(0)+exp2 -> P, fr tile1 -> slot1,
    //      hr tile0 -> slot0 ----
    #pragma unroll
    for (int j = 0; j < 2; j++)
        fr[0][j] = *(const short8*)&ftb[(size_t)((half*2 + j)*16 + l15)*32 + quad*8];
    {
        float4v z = {0.f,0.f,0.f,0.f};
        float4v s0v = __builtin_amdgcn_mfma_f32_16x16x32_bf16(fr[0][0], gfrag.v, z, 0, 0, 0);
        float4v s1v = __builtin_amdgcn_mfma_f32_16x16x32_bf16(fr[0][1], gfrag.v, z, 0, 0, 0);
        float e0 = ex2(s0v[0]), e1 = ex2(s0v[1]), e2 = ex2(s0v[2]), e3 = ex2(s0v[3]);
        float e4 = ex2(s1v[0]), e5 = ex2(s1v[1]), e6 = ex2(s1v[2]), e7 = ex2(s1v[3]);
        l_acc += (e0 + e1) + (e2 + e3) + (e4 + e5) + (e6 + e7);
        P = make_uint4(cvtpk(e0, e1), cvtpk(e2, e3), cvtpk(e4, e5), cvtpk(e6, e7));
    }
    #pragma unroll
    for (int j = 0; j < 2; j++)
        fr[1][j] = *(const short8*)&ftb[(size_t)(64 + (half*2 + j)*16 + l15)*32 + quad*8];
    #pragma unroll
    for (int grp = 0; grp < 2; grp++)
        #pragma unroll
        for (int ctl = 0; ctl < 2; ctl++)
            hr[0][grp][ctl] = *(const short8*)&h3b[(((size_t)(grp*16 + w*2 + ctl)) << 9) + lane*8];

    // Per-iter i (buf u=i&1):
    //  1. hr prefetch tile i+1 -> hr[u^1]  (PRE-barrier; consumed in iter
    //     i+1's PV; same-wave WAR vs PV(i-1)'s read of hr[u^1] is
    //     program-order-safe)
    //  2. pB[u] write of P(i)  3. lgkm-barrier
    //  4. fr prefetch tile i+2 -> fr[u] (no wrap: slop reads stay in ws)
    //  5. S^T(i+1) from fr[u^1] + exp2 -> P
    //  6. PV(i) from hr[u], pB[u] under setprio(1)
    // pB[u] WAR-safe: last readers (iter i-2) consumed pre-barrier(i-1).
#define ATTN_STEP(u, i, DO_NEXT) do {                                          \
    if (DO_NEXT) {                                                             \
      const int nh = (i) + 1;                                                  \
      _Pragma("unroll")                                                        \
      for (int grp = 0; grp < 2; grp++)                                        \
        _Pragma("unroll")                                                      \
        for (int ctl = 0; ctl < 2; ctl++)                                      \
          hr[(u)^1][grp][ctl] = *(const short8*)&h3b[(((size_t)((nh*2 + grp)*16 + w*2 + ctl)) << 9) + lane*8]; \
    }                                                                          \
    pB[u][half][qt_w][lane] = P;                                               \
    lds_barrier();                                                             \
    if (DO_NEXT) {                                                             \
      const int nf = (i) + 2;                                                  \
      _Pragma("unroll")                                                        \
      for (int j = 0; j < 2; j++)                                              \
        fr[u][j] = *(const short8*)&ftb[(size_t)(nf*64 + (half*2 + j)*16 + l15)*32 + quad*8]; \
      float4v z = {0.f,0.f,0.f,0.f};                                           \
      float4v s0v = __builtin_amdgcn_mfma_f32_16x16x32_bf16(fr[(u)^1][0], gfrag.v, z, 0, 0, 0); \
      float4v s1v = __builtin_amdgcn_mfma_f32_16x16x32_bf16(fr[(u)^1][1], gfrag.v, z, 0, 0, 0); \
      float e0 = ex2(s0v[0]), e1 = ex2(s0v[1]), e2 = ex2(s0v[2]), e3 = ex2(s0v[3]); \
      float e4 = ex2(s1v[0]), e5 = ex2(s1v[1]), e6 = ex2(s1v[2]), e7 = ex2(s1v[3]); \
      l_acc += (e0 + e1) + (e2 + e3) + (e4 + e5) + (e6 + e7);                  \
      P = make_uint4(cvtpk(e0, e1), cvtpk(e2, e3), cvtpk(e4, e5), cvtpk(e6, e7)); \
    }                                                                          \
    __builtin_amdgcn_s_setprio(1);                                             \
    _Pragma("unroll")                                                          \
    for (int grp = 0; grp < 2; grp++) {                                        \
      _Pragma("unroll")                                                        \
      for (int qt = 0; qt < 4; qt++) {                                         \
        union { uint4 uu; short8 v; } bq;                                      \
        bq.uu = pB[u][grp][qt][lane];                                          \
        _Pragma("unroll")                                                      \
        for (int ctl = 0; ctl < 2; ctl++)                                      \
          acc[ctl][qt] = __builtin_amdgcn_mfma_f32_16x16x32_bf16(hr[u][grp][ctl], bq.v, acc[ctl][qt], 0, 0, 0); \
      }                                                                        \
    }                                                                          \
    __builtin_amdgcn_s_setprio(0);                                             \
  } while (0)

    for (int i0 = 0; i0 < 62; i0 += 2) {
        ATTN_STEP(0, i0, 1);
        ATTN_STEP(1, i0 + 1, 1);
    }
    ATTN_STEP(0, 62, 1);   // computes S^T(63)+P; fr prefetch (tile 64) is dead slop
    ATTN_STEP(1, 63, 0);   // peeled tail: write P(63), PV(63) only
#undef ATTN_STEP

    // ---- l: reduce over quads; combine halves via LDS ----
    l_acc += __shfl_xor(l_acc, 16, 64);
    l_acc += __shfl_xor(l_acc, 32, 64);
    if (quad == 0) l_l[qt_w][l15][half] = l_acc;
    __syncthreads();

    const float gamma = *gamma_p;
    float linv[4];
    #pragma unroll
    for (int qt = 0; qt < 4; qt++) linv[qt] = 1.f / (l_l[qt][l15][0] + l_l[qt][l15][1]);
    #pragma unroll
    for (int ctl = 0; ctl < 2; ctl++) {
        #pragma unroll
        for (int r = 0; r < 4; r++) {
            int c = w*32 + ctl*16 + quad*4 + r;
            size_t base = (size_t)(b*CH + c)*HWN + q0;
            #pragma unroll
            for (int qt = 0; qt < 4; qt++) {
                size_t o = base + qt*16 + l15;
                out[o] = gamma * acc[ctl][qt][r] * linv[qt] + x[o];
            }
        }
    }
}

extern "C" void kernel_launch(void* const* d_in, const int* in_sizes, int n_in,
                              void* d_out, int out_size, void* d_ws, size_t ws_size,
                              hipStream_t stream) {
    const float* x     = (const float*)d_in[0];
    const float* Wf    = (const float*)d_in[1];
    const float* bf_   = (const float*)d_in[2];
    const float* Wg    = (const float*)d_in[3];
    const float* bg    = (const float*)d_in[4];
    const float* Wh    = (const float*)d_in[5];
    const float* bh    = (const float*)d_in[6];
    const float* gamma = (const float*)d_in[7];
    float* out = (float*)d_out;

    // ws: xt 16.8MB | ft 2MB | g 1MB | h3 16.8MB | Wbf 147KB | bcat
    unsigned short* xt   = (unsigned short*)d_ws;
    unsigned short* ftp  = xt  + (size_t)BATCH*HWN*CH;
    unsigned short* g    = ftp + (size_t)BATCH*HWN*32;
    unsigned short* h3   = g   + (size_t)BATCH*DQK*HWN;
    unsigned short* Wbf  = h3  + (size_t)BATCH*128*16*512;
    float*          bcat = (float*)(Wbf + 288*CH);

    xt_wcast_kernel<<<dim3(HWN/64, CH/64, BATCH), 256, 0, stream>>>(
        x, Wf, bf_, Wg, bg, Wh, bh, xt, Wbf, bcat);
    proj_kernel<<<dim3(HWN/64, BATCH, 2), 256, 0, stream>>>(xt, Wbf, bcat, ftp, g, h3);
    attn_kernel<<<dim3((HWN/64)*BATCH), 512, 0, stream>>>(ftp, g, h3, x, gamma, out);
}

// Round 11
// 205.357 us; speedup vs baseline: 1.2402x; 1.0373x over previous
//
#include <hip/hip_runtime.h>
#include <math.h>

#define BATCH 8
#define CH    256
#define HWN   4096
#define DQK   16

typedef __attribute__((ext_vector_type(8))) short short8;
typedef __attribute__((ext_vector_type(4))) float float4v;

#define L2E 1.4426950408889634f

__device__ __forceinline__ unsigned short f2bf(float f) {
    union { float f; unsigned int u; } v; v.f = f;
    unsigned int r = v.u + 0x7FFF + ((v.u >> 16) & 1);   // RNE
    return (unsigned short)(r >> 16);
}
// HW packed f32->bf16 convert (RNE): %1 -> low16, %2 -> high16
__device__ __forceinline__ unsigned int cvtpk(float lo, float hi) {
    unsigned int r;
    asm("v_cvt_pk_bf16_f32 %0, %1, %2" : "=v"(r) : "v"(lo), "v"(hi));
    return r;
}
// 2^x via hardware v_exp_f32, compiler-managed TRANS hazards
__device__ __forceinline__ float ex2(float x) {
#if __has_builtin(__builtin_amdgcn_exp2f)
    return __builtin_amdgcn_exp2f(x);
#else
    return exp2f(x);
#endif
}
// Block barrier WITHOUT the vmcnt(0) drain __syncthreads carries (T4):
// only LDS ordering is required for the pB exchange; global prefetches
// stay in flight across the barrier.
__device__ __forceinline__ void lds_barrier() {
    asm volatile("s_waitcnt lgkmcnt(0)" ::: "memory");
    __builtin_amdgcn_s_barrier();
}
// ft row permutation: stored row s holds key m with s4=m2, s3=m4, s2=m3
// (bits 0,1,5+ unchanged). Makes S^T output registers align with PV B-frag
// slots in the SAME lane (no cross-lane transpose needed).
__device__ __forceinline__ int perm_ft(int m) {
    return (m & ~28) | ((m & 24) >> 1) | ((m & 4) << 2);
}

// ---------------- kernel 0: W_cat -> bf16, biases -> bcat ----------------
__global__ __launch_bounds__(256) void wcast_kernel(
    const float* __restrict__ Wf, const float* __restrict__ bf_,
    const float* __restrict__ Wg, const float* __restrict__ bg,
    const float* __restrict__ Wh, const float* __restrict__ bh,
    unsigned short* __restrict__ Wbf, float* __restrict__ bcat)
{
    const int r = blockIdx.x;   // 288 rows
    const int t = threadIdx.x;  // 256 cols
    const float* src = (r < 16) ? (Wf + r*CH) : (r < 32) ? (Wg + (r-16)*CH) : (Wh + (r-32)*CH);
    Wbf[r*CH + t] = f2bf(src[t]);
    if (t == 0) bcat[r] = (r < 16) ? bf_[r] : (r < 32) ? bg[r-16] : bh[r-32];
}

// ---------------- kernel 1: FUSED transpose + MFMA projection ----------------
// R11: kills the xt tensor (was 134 MB read + 67 MB write + 33.5 MB
// re-read). Block = 32 px x 256 c, grid (128, 8) = 1024 blocks (4/CU).
// Stage x[b][*][px0..31] -> LDS tile[32][264] bf16 (float4 loads over px,
// cvt_pk; row = 528 B, 16B-aligned, bank-uniform for b128). One barrier.
// Wave split covers all 18 W_cat rows in one pass over x:
//   wave w: rt-group (w>>1)*9, px-half (w&1)*16. acc 9x4 = 36 AGPR.
// Register audit (session ceiling: launch_bounds(256,4) -> 128/wave):
// 36 AGPR + frag 8 + staging ~10 + addr ~25 ~= 80, no spill.
// Epilogue identical to prior proj (ft perm_ft rows PRE-SCALED by log2e,
// g, h3 frag layout); mt = blockIdx.x exactly (32-px block = 1 mt... 32
// px within one mt granule: mt = px0>>5).
__global__ __launch_bounds__(256, 4) void proj_kernel(
    const float* __restrict__ x, const unsigned short* __restrict__ Wbf,
    const float* __restrict__ bcat,
    unsigned short* __restrict__ ft, unsigned short* __restrict__ g,
    unsigned short* __restrict__ h3)
{
    const int t    = threadIdx.x;
    const int px0  = blockIdx.x * 32;
    const int b    = blockIdx.y;
    const int lane = t & 63, w = t >> 6, l15 = lane & 15, quad = lane >> 4;
    const int rtbase = (w >> 1) * 9;      // 0 or 9
    const int pxh    = (w & 1) * 16;      // px-half within the 32-px tile

    __shared__ unsigned short tile[32][264];   // 16.5 KB, rows 16B-aligned

    // ---- stage: x[b][c][px0+px4 .. +3] -> tile[px][c] ----
    const int px4 = (t & 7) * 4;          // 0..28
    const int c0  = t >> 3;               // 0..31
    #pragma unroll
    for (int j = 0; j < 8; j++) {
        int c = c0 + j*32;
        float4 v = *(const float4*)&x[(size_t)(b*CH + c)*HWN + px0 + px4];
        unsigned int u01 = cvtpk(v.x, v.y), u23 = cvtpk(v.z, v.w);
        tile[px4+0][c] = (unsigned short)u01;
        tile[px4+1][c] = (unsigned short)(u01 >> 16);
        tile[px4+2][c] = (unsigned short)u23;
        tile[px4+3][c] = (unsigned short)(u23 >> 16);
    }
    __syncthreads();

    float4v acc[9];
    #pragma unroll
    for (int rt = 0; rt < 9; rt++) acc[rt] = (float4v){0.f,0.f,0.f,0.f};

    const unsigned short* wrow = &Wbf[(size_t)l15*CH + quad*8];

    #pragma unroll
    for (int ks = 0; ks < 8; ks++) {
        short8 afrag = *(const short8*)&tile[pxh + l15][quad*8 + ks*32];
        #pragma unroll
        for (int rt = 0; rt < 9; rt++) {
            short8 bfrag = *(const short8*)&wrow[(size_t)(rtbase + rt)*16*CH + ks*32];
            acc[rt] = __builtin_amdgcn_mfma_f32_16x16x32_bf16(afrag, bfrag, acc[rt], 0, 0, 0);
        }
    }

    const int pxl = px0 + pxh + quad*4;   // this lane's px base (+r)
    const int mt  = px0 >> 5;             // = blockIdx.x
    const int sub = ((w & 1)*2 + (quad >> 1))*128 + l15*8 + (quad & 1)*4;
    #pragma unroll
    for (int rt = 0; rt < 9; rt++) {
        const int R = rtbase + rt;        // uniform per wave
        if (R == 0) {                     // -> ft at perm_ft rows, * log2e
            float bv = bcat[l15];
            const int s0 = perm_ft(pxl);  // r only touches bits 0,1
            unsigned int p01 = cvtpk((acc[rt][0] + bv)*L2E, (acc[rt][1] + bv)*L2E);
            unsigned int p23 = cvtpk((acc[rt][2] + bv)*L2E, (acc[rt][3] + bv)*L2E);
            unsigned short* fp0 = &ft[((size_t)b*HWN + s0)*32];
            fp0[l15]       = (unsigned short)p01;         fp0[16 + l15]  = 0;
            fp0[32 + l15]  = (unsigned short)(p01 >> 16); fp0[48 + l15]  = 0;
            fp0[64 + l15]  = (unsigned short)p23;         fp0[80 + l15]  = 0;
            fp0[96 + l15]  = (unsigned short)(p23 >> 16); fp0[112 + l15] = 0;
        } else if (R == 1) {              // -> g (4 consecutive px: uint2)
            float bv = bcat[16 + l15];
            unsigned int a01 = cvtpk(acc[rt][0] + bv, acc[rt][1] + bv);
            unsigned int a23 = cvtpk(acc[rt][2] + bv, acc[rt][3] + bv);
            *(uint2*)&g[(size_t)(b*DQK + l15)*HWN + pxl] = make_uint2(a01, a23);
        } else {                          // -> h3 frag layout
            float bv = bcat[R*16 + l15];
            unsigned int u0 = cvtpk(acc[rt][0] + bv, acc[rt][1] + bv);
            unsigned int u1 = cvtpk(acc[rt][2] + bv, acc[rt][3] + bv);
            *(uint2*)&h3[(((size_t)((b*128 + mt)*16 + (R-2))) << 9) + sub] = make_uint2(u0, u1);
        }
    }
}

// ---------------- kernel 2: MFMA flash attention, 8 waves ----------------
// FROZEN at R7 (best measured: 86.0 us, VGPR 60, no spill). Block = 512
// thr, (batch, 64-q tile), grid 512. 1 key-tile/barrier, pB[2] dbuf,
// software pipeline, lgkm-only barrier, pre-barrier hr prefetch, exp2 on
// L2E-prescaled ft, setprio around PV. Session lessons: >96 live VGPRs
// spills (R3/R8/R9); trading LDS reads for L2 loads regresses (R6);
// 32-q blocks halve arithmetic intensity (R5).
__global__ __launch_bounds__(512, 4) void attn_kernel(
    const unsigned short* __restrict__ ft, const unsigned short* __restrict__ g,
    const unsigned short* __restrict__ h3, const float* __restrict__ x,
    const float* __restrict__ gamma_p, float* __restrict__ out)
{
    const int t    = threadIdx.x;
    const int b    = blockIdx.x & 7;          // batch -> XCD pin
    const int q0   = (blockIdx.x >> 3) * 64;
    const int lane = t & 63, w = t >> 6, l15 = lane & 15, quad = lane >> 4;
    const int qt_w = w >> 1, half = w & 1;

    __shared__ __align__(16) uint4 pB[2][2][4][64];   // [buf][half][qt][lane] 16 KB
    __shared__ float l_l[4][16][2];

    union { short8 v; unsigned short u[8]; } gfrag;   // B[k=quad*8+j][q=l15] of q-tile qt_w
    #pragma unroll
    for (int j = 0; j < 8; j++) {
        int k = quad*8 + j;
        gfrag.u[j] = (k < DQK) ? g[(size_t)(b*DQK + k)*HWN + q0 + qt_w*16 + l15] : (unsigned short)0;
    }

    const unsigned short* ftb = ft + (size_t)b*HWN*32;
    const unsigned short* h3b = h3 + ((size_t)b << 20);

    short8 fr[2][2], hr[2][2][2];
    float4v acc[2][4];
    #pragma unroll
    for (int i = 0; i < 2; i++)
        #pragma unroll
        for (int j = 0; j < 4; j++) acc[i][j] = (float4v){0.f,0.f,0.f,0.f};
    float l_acc = 0.f;
    uint4 P;

    // ---- prologue: fr tile0 -> slot0, S^T(0)+exp2 -> P, fr tile1 -> slot1,
    //      hr tile0 -> slot0 ----
    #pragma unroll
    for (int j = 0; j < 2; j++)
        fr[0][j] = *(const short8*)&ftb[(size_t)((half*2 + j)*16 + l15)*32 + quad*8];
    {
        float4v z = {0.f,0.f,0.f,0.f};
        float4v s0v = __builtin_amdgcn_mfma_f32_16x16x32_bf16(fr[0][0], gfrag.v, z, 0, 0, 0);
        float4v s1v = __builtin_amdgcn_mfma_f32_16x16x32_bf16(fr[0][1], gfrag.v, z, 0, 0, 0);
        float e0 = ex2(s0v[0]), e1 = ex2(s0v[1]), e2 = ex2(s0v[2]), e3 = ex2(s0v[3]);
        float e4 = ex2(s1v[0]), e5 = ex2(s1v[1]), e6 = ex2(s1v[2]), e7 = ex2(s1v[3]);
        l_acc += (e0 + e1) + (e2 + e3) + (e4 + e5) + (e6 + e7);
        P = make_uint4(cvtpk(e0, e1), cvtpk(e2, e3), cvtpk(e4, e5), cvtpk(e6, e7));
    }
    #pragma unroll
    for (int j = 0; j < 2; j++)
        fr[1][j] = *(const short8*)&ftb[(size_t)(64 + (half*2 + j)*16 + l15)*32 + quad*8];
    #pragma unroll
    for (int grp = 0; grp < 2; grp++)
        #pragma unroll
        for (int ctl = 0; ctl < 2; ctl++)
            hr[0][grp][ctl] = *(const short8*)&h3b[(((size_t)(grp*16 + w*2 + ctl)) << 9) + lane*8];

    // Per-iter i (buf u=i&1):
    //  1. hr prefetch tile i+1 -> hr[u^1]  (PRE-barrier; consumed in iter
    //     i+1's PV; same-wave WAR vs PV(i-1)'s read of hr[u^1] is
    //     program-order-safe)
    //  2. pB[u] write of P(i)  3. lgkm-barrier
    //  4. fr prefetch tile i+2 -> fr[u] (no wrap: slop reads stay in ws)
    //  5. S^T(i+1) from fr[u^1] + exp2 -> P
    //  6. PV(i) from hr[u], pB[u] under setprio(1)
    // pB[u] WAR-safe: last readers (iter i-2) consumed pre-barrier(i-1).
#define ATTN_STEP(u, i, DO_NEXT) do {                                          \
    if (DO_NEXT) {                                                             \
      const int nh = (i) + 1;                                                  \
      _Pragma("unroll")                                                        \
      for (int grp = 0; grp < 2; grp++)                                        \
        _Pragma("unroll")                                                      \
        for (int ctl = 0; ctl < 2; ctl++)                                      \
          hr[(u)^1][grp][ctl] = *(const short8*)&h3b[(((size_t)((nh*2 + grp)*16 + w*2 + ctl)) << 9) + lane*8]; \
    }                                                                          \
    pB[u][half][qt_w][lane] = P;                                               \
    lds_barrier();                                                             \
    if (DO_NEXT) {                                                             \
      const int nf = (i) + 2;                                                  \
      _Pragma("unroll")                                                        \
      for (int j = 0; j < 2; j++)                                              \
        fr[u][j] = *(const short8*)&ftb[(size_t)(nf*64 + (half*2 + j)*16 + l15)*32 + quad*8]; \
      float4v z = {0.f,0.f,0.f,0.f};                                           \
      float4v s0v = __builtin_amdgcn_mfma_f32_16x16x32_bf16(fr[(u)^1][0], gfrag.v, z, 0, 0, 0); \
      float4v s1v = __builtin_amdgcn_mfma_f32_16x16x32_bf16(fr[(u)^1][1], gfrag.v, z, 0, 0, 0); \
      float e0 = ex2(s0v[0]), e1 = ex2(s0v[1]), e2 = ex2(s0v[2]), e3 = ex2(s0v[3]); \
      float e4 = ex2(s1v[0]), e5 = ex2(s1v[1]), e6 = ex2(s1v[2]), e7 = ex2(s1v[3]); \
      l_acc += (e0 + e1) + (e2 + e3) + (e4 + e5) + (e6 + e7);                  \
      P = make_uint4(cvtpk(e0, e1), cvtpk(e2, e3), cvtpk(e4, e5), cvtpk(e6, e7)); \
    }                                                                          \
    __builtin_amdgcn_s_setprio(1);                                             \
    _Pragma("unroll")                                                          \
    for (int grp = 0; grp < 2; grp++) {                                        \
      _Pragma("unroll")                                                        \
      for (int qt = 0; qt < 4; qt++) {                                         \
        union { uint4 uu; short8 v; } bq;                                      \
        bq.uu = pB[u][grp][qt][lane];                                          \
        _Pragma("unroll")                                                      \
        for (int ctl = 0; ctl < 2; ctl++)                                      \
          acc[ctl][qt] = __builtin_amdgcn_mfma_f32_16x16x32_bf16(hr[u][grp][ctl], bq.v, acc[ctl][qt], 0, 0, 0); \
      }                                                                        \
    }                                                                          \
    __builtin_amdgcn_s_setprio(0);                                             \
  } while (0)

    for (int i0 = 0; i0 < 62; i0 += 2) {
        ATTN_STEP(0, i0, 1);
        ATTN_STEP(1, i0 + 1, 1);
    }
    ATTN_STEP(0, 62, 1);   // computes S^T(63)+P; fr prefetch (tile 64) is dead slop
    ATTN_STEP(1, 63, 0);   // peeled tail: write P(63), PV(63) only
#undef ATTN_STEP

    // ---- l: reduce over quads; combine halves via LDS ----
    l_acc += __shfl_xor(l_acc, 16, 64);
    l_acc += __shfl_xor(l_acc, 32, 64);
    if (quad == 0) l_l[qt_w][l15][half] = l_acc;
    __syncthreads();

    const float gamma = *gamma_p;
    float linv[4];
    #pragma unroll
    for (int qt = 0; qt < 4; qt++) linv[qt] = 1.f / (l_l[qt][l15][0] + l_l[qt][l15][1]);
    #pragma unroll
    for (int ctl = 0; ctl < 2; ctl++) {
        #pragma unroll
        for (int r = 0; r < 4; r++) {
            int c = w*32 + ctl*16 + quad*4 + r;
            size_t base = (size_t)(b*CH + c)*HWN + q0;
            #pragma unroll
            for (int qt = 0; qt < 4; qt++) {
                size_t o = base + qt*16 + l15;
                out[o] = gamma * acc[ctl][qt][r] * linv[qt] + x[o];
            }
        }
    }
}

extern "C" void kernel_launch(void* const* d_in, const int* in_sizes, int n_in,
                              void* d_out, int out_size, void* d_ws, size_t ws_size,
                              hipStream_t stream) {
    const float* x     = (const float*)d_in[0];
    const float* Wf    = (const float*)d_in[1];
    const float* bf_   = (const float*)d_in[2];
    const float* Wg    = (const float*)d_in[3];
    const float* bg    = (const float*)d_in[4];
    const float* Wh    = (const float*)d_in[5];
    const float* bh    = (const float*)d_in[6];
    const float* gamma = (const float*)d_in[7];
    float* out = (float*)d_out;

    // ws: ft 2MB | g 1MB | h3 16.8MB | Wbf 147KB | bcat  (xt eliminated)
    unsigned short* ftp  = (unsigned short*)d_ws;
    unsigned short* g    = ftp + (size_t)BATCH*HWN*32;
    unsigned short* h3   = g   + (size_t)BATCH*DQK*HWN;
    unsigned short* Wbf  = h3  + (size_t)BATCH*128*16*512;
    float*          bcat = (float*)(Wbf + 288*CH);

    wcast_kernel<<<dim3(288), 256, 0, stream>>>(Wf, bf_, Wg, bg, Wh, bh, Wbf, bcat);
    proj_kernel<<<dim3(HWN/32, BATCH), 256, 0, stream>>>(x, Wbf, bcat, ftp, g, h3);
    attn_kernel<<<dim3((HWN/64)*BATCH), 512, 0, stream>>>(ftp, g, h3, x, gamma, out);
}